// Round 7
// baseline (85.402 us; speedup 1.0000x reference)
//
#include <hip/hip_runtime.h>

#define SS 4096
#define DD 64
#define NH 16
#define QB 128
#define NQB (SS / QB)      // 32
#define KVT 64
#define NKV (SS / KVT)     // 64
#define TILE_BYTES 8192    // 64 x 64 bf16

typedef float  fx4    __attribute__((ext_vector_type(4)));
typedef __bf16 bf16x8 __attribute__((ext_vector_type(8)));
typedef short  sx4    __attribute__((ext_vector_type(4)));

typedef __attribute__((address_space(1))) const unsigned int GU32;
typedef __attribute__((address_space(3))) unsigned int       LU32;

__device__ __forceinline__ void gload16(const void* g, void* l) {
    __builtin_amdgcn_global_load_lds((GU32*)g, (LU32*)l, 16, 0, 0);
}

__device__ __forceinline__ float fast_exp2(float x) {
    return __builtin_amdgcn_exp2f(x);   // v_exp_f32: 2^x
}

// ---------------- pre-pass: f32 K/V -> bf16 swizzled tile images ----------------
__global__ __launch_bounds__(256)
void prep_kernel(const float* __restrict__ Kg, const float* __restrict__ Vg,
                 char* __restrict__ Kimg, char* __restrict__ Vimg)
{
    __shared__ __bf16 lv[64][72];
    const int tid = threadIdx.x;
    const int h = (int)blockIdx.x >> 6;
    const int t = (int)blockIdx.x & 63;
    const int r = tid >> 2;                       // 0..63
    const size_t rowbase = ((size_t)h * SS + (size_t)t * KVT) * DD;

    // ---- K ----
    {
        char* kdst = Kimg + (size_t)(h * NKV + t) * TILE_BYTES;
        const float* src = Kg + rowbase + (size_t)r * DD;
#pragma unroll
        for (int cc = 0; cc < 2; ++cc) {
            const int c = (tid & 3) * 2 + cc;     // 0..7
            fx4 f0 = *(const fx4*)(src + c * 8);
            fx4 f1 = *(const fx4*)(src + c * 8 + 4);
            bf16x8 b;
#pragma unroll
            for (int j = 0; j < 4; ++j) { b[j] = (__bf16)f0[j]; b[4 + j] = (__bf16)f1[j]; }
            *(bf16x8*)(kdst + r * 128 + ((c ^ (r & 7)) << 4)) = b;
        }
    }

    // ---- V: load tile to LDS (row-major), then write transposed ----
    {
        const float* src = Vg + rowbase + (size_t)r * DD + (tid & 3) * 16;
#pragma unroll
        for (int qq = 0; qq < 4; ++qq) {
            fx4 f = *(const fx4*)(src + qq * 4);
#pragma unroll
            for (int j = 0; j < 4; ++j) lv[r][(tid & 3) * 16 + qq * 4 + j] = (__bf16)f[j];
        }
    }
    __syncthreads();
    {
        char* vdst = Vimg + (size_t)(h * NKV + t) * TILE_BYTES;
        const int d = r;                          // VT row
#pragma unroll
        for (int cc = 0; cc < 2; ++cc) {
            const int c = (tid & 3) * 2 + cc;     // k-chunk 0..7
            bf16x8 b;
#pragma unroll
            for (int j = 0; j < 8; ++j) b[j] = lv[c * 8 + j][d];
            *(bf16x8*)(vdst + d * 128 + ((c ^ (d & 7)) << 4)) = b;
        }
    }
}

// ---------------- main kernel: 4 waves x 32 q-rows, arity-2 KV split ----------------
// 1024 blocks. Block b: h=b&15, j=b>>4; hi=j>>5, i=j&31, c=(i>>4)&1, k=i&15;
//   p = hi ? 15-k : 16+k  (chunk sizes: heavy 17..33, light 17..2; b and b+512
//   land on the same CU under round-robin XCD fill -> per-CU sum constant)
// chunk c=0: tiles [0, p+1)       -> raw f32 acc to Og, l/m -> lm planes 0/1
// chunk c=1: tiles [p+1, 2p+2)    -> bf16 acc to accY,     l/m -> lm planes 2/3
__global__ __launch_bounds__(256, 4)
void attn_fwd(const float* __restrict__ Qg, const char* __restrict__ Kimg,
              const char* __restrict__ Vimg, float* __restrict__ Og,
              unsigned short* __restrict__ accY, float* __restrict__ lmW)
{
    __shared__ __align__(16) char lK[2][TILE_BYTES];
    __shared__ __align__(16) char lV[2][TILE_BYTES];

    const int tid  = threadIdx.x;
    const int wid  = tid >> 6;                    // 0..3
    const int lane = tid & 63;
    const int lr   = lane & 15;
    const int g    = lane >> 4;

    const int b  = (int)blockIdx.x;               // 0..1023
    const int h  = b & 15;
    const int j  = b >> 4;                        // 0..63
    const int hi = j >> 5;
    const int ii = j & 31;
    const int c  = (ii >> 4) & 1;
    const int kk4 = ii & 15;
    const int p  = hi ? (15 - kk4) : (16 + kk4);

    const int t0 = c ? (p + 1) : 0;
    const int t1 = c ? (2 * p + 2) : (p + 1);

    const int q0 = p * QB + wid * 32;             // wave owns 32 q rows (2 subtiles)

    const float* Qh = Qg + (size_t)h * SS * DD;
    float*       Oh = Og + (size_t)h * SS * DD;
    const char*  Kh = Kimg + (size_t)(h * NKV) * TILE_BYTES;
    const char*  Vh = Vimg + (size_t)(h * NKV) * TILE_BYTES;

    const float QSCALE = 0.125f * 1.44269504088896f;   // 1/sqrt(64) * log2(e)

    // Q fragments (held all kernel)
    bf16x8 qa[2][2];
#pragma unroll
    for (int u = 0; u < 2; ++u) {
        const int qrow = q0 + 16 * u + lr;
#pragma unroll
        for (int h2 = 0; h2 < 2; ++h2) {
            const float* src = Qh + (size_t)qrow * DD + h2 * 32 + g * 8;
            fx4 f0 = *(const fx4*)(src);
            fx4 f1 = *(const fx4*)(src + 4);
            bf16x8 tq;
#pragma unroll
            for (int jj = 0; jj < 4; ++jj) {
                tq[jj]     = (__bf16)(f0[jj] * QSCALE);
                tq[jj + 4] = (__bf16)(f1[jj] * QSCALE);
            }
            qa[u][h2] = tq;
        }
    }

    fx4 acc[2][4];
#pragma unroll
    for (int u = 0; u < 2; ++u)
#pragma unroll
        for (int d0 = 0; d0 < 4; ++d0) acc[u][d0] = (fx4){0.f, 0.f, 0.f, 0.f};
    float m_run = -1e30f;           // wave-uniform running max (log2 units)
    float l_run[2] = {0.f, 0.f};    // lane-local partial row sums

    // staging: waves 0,1 -> K tile halves; waves 2,3 -> V tile halves (4KB/wave)
#define STAGE(buf, tt)                                                          \
    do {                                                                        \
        const char* img_ = (wid < 2) ? Kh : Vh;                                 \
        char* dst_ = ((wid < 2) ? &lK[buf][0] : &lV[buf][0]) + (wid & 1) * 4096;\
        const char* src_ = img_ + (size_t)(tt) * TILE_BYTES + (wid & 1) * 4096  \
                           + lane * 16;                                         \
        gload16(src_,        dst_);                                             \
        gload16(src_ + 1024, dst_ + 1024);                                      \
        gload16(src_ + 2048, dst_ + 2048);                                      \
        gload16(src_ + 3072, dst_ + 3072);                                      \
    } while (0)

    STAGE(0, t0);
    __syncthreads();

    int cur = 0;
    for (int t = t0; t < t1; ++t) {
        if (t + 1 < t1) STAGE(cur ^ 1, t + 1);   // prefetch next tile

        // ---- QK^T (swapped: A=K tile rows, B=Q) ----
        float s[2][4][4];
        __builtin_amdgcn_s_setprio(1);
#pragma unroll
        for (int ks = 0; ks < 4; ++ks) {
            const int row = ks * 16 + lr;
            const char* base = &lK[cur][row * 128];
            const bf16x8 ka0 = *(const bf16x8*)(base + (((g    ) ^ (row & 7)) << 4));
            const bf16x8 ka1 = *(const bf16x8*)(base + (((g ^ 4) ^ (row & 7)) << 4));
#pragma unroll
            for (int u = 0; u < 2; ++u) {
                fx4 st = (fx4){0.f, 0.f, 0.f, 0.f};
                st = __builtin_amdgcn_mfma_f32_16x16x32_bf16(ka0, qa[u][0], st, 0, 0, 0);
                st = __builtin_amdgcn_mfma_f32_16x16x32_bf16(ka1, qa[u][1], st, 0, 0, 0);
#pragma unroll
                for (int r = 0; r < 4; ++r) s[u][ks][r] = st[r];
            }
        }
        __builtin_amdgcn_s_setprio(0);

        // ---- causal mask (tile crosses diagonal iff t >= 2p) ----
        if (t >= 2 * p) {
            const int kv0 = t * KVT;
#pragma unroll
            for (int u = 0; u < 2; ++u) {
                const int qrow = q0 + 16 * u + lr;
#pragma unroll
                for (int ks = 0; ks < 4; ++ks)
#pragma unroll
                    for (int r = 0; r < 4; ++r) {
                        const int kvi = kv0 + ks * 16 + 4 * g + r;
                        if (kvi > qrow) s[u][ks][r] = -1e30f;
                    }
            }
        }

        // ---- softmax: shuffle-free check, rare wave-uniform rescale ----
        float m4[2][4];
#pragma unroll
        for (int u = 0; u < 2; ++u)
#pragma unroll
            for (int ks = 0; ks < 4; ++ks)
                m4[u][ks] = fmaxf(fmaxf(s[u][ks][0], s[u][ks][1]),
                                  fmaxf(s[u][ks][2], s[u][ks][3]));
        const float tm = fmaxf(
            fmaxf(fmaxf(m4[0][0], m4[0][1]), fmaxf(m4[0][2], m4[0][3])),
            fmaxf(fmaxf(m4[1][0], m4[1][1]), fmaxf(m4[1][2], m4[1][3])));

        if (__any(tm > m_run + 8.0f)) {           // rare after first tile
            float wm = tm;
            wm = fmaxf(wm, __shfl_xor(wm, 1));
            wm = fmaxf(wm, __shfl_xor(wm, 2));
            wm = fmaxf(wm, __shfl_xor(wm, 4));
            wm = fmaxf(wm, __shfl_xor(wm, 8));
            wm = fmaxf(wm, __shfl_xor(wm, 16));
            wm = fmaxf(wm, __shfl_xor(wm, 32));   // wave max, uniform
            const float alpha = fast_exp2(m_run - wm);
            m_run = wm;
            l_run[0] *= alpha; l_run[1] *= alpha;
#pragma unroll
            for (int u = 0; u < 2; ++u)
#pragma unroll
                for (int d0 = 0; d0 < 4; ++d0) {
                    fx4 a = acc[u][d0];
                    a[0] *= alpha; a[1] *= alpha; a[2] *= alpha; a[3] *= alpha;
                    acc[u][d0] = a;
                }
        }

        sx4 pa[2][4];
#pragma unroll
        for (int u = 0; u < 2; ++u) {
            float e[4][4];
#pragma unroll
            for (int ks = 0; ks < 4; ++ks)
#pragma unroll
                for (int r = 0; r < 4; ++r)
                    e[ks][r] = fast_exp2(s[u][ks][r] - m_run);
            const float u0 = (e[0][0] + e[0][1]) + (e[0][2] + e[0][3]);
            const float u1 = (e[1][0] + e[1][1]) + (e[1][2] + e[1][3]);
            const float u2 = (e[2][0] + e[2][1]) + (e[2][2] + e[2][3]);
            const float u3 = (e[3][0] + e[3][1]) + (e[3][2] + e[3][3]);
            l_run[u] += (u0 + u1) + (u2 + u3);
#pragma unroll
            for (int ks = 0; ks < 4; ++ks) {
                sx4 t4;
#pragma unroll
                for (int jj = 0; jj < 4; ++jj) {
                    const __bf16 pb = (__bf16)e[ks][jj];
                    t4[jj] = __builtin_bit_cast(short, pb);
                }
                pa[u][ks] = t4;
            }
        }

        // ---- PV: P fragments already in MFMA A-layout; V^T read swizzled ----
        __builtin_amdgcn_s_setprio(1);
#pragma unroll
        for (int ks = 0; ks < 4; ++ks) {
            const int s0 = ks * 2 + (g >> 1);     // k-chunk slot
#pragma unroll
            for (int d0 = 0; d0 < 4; ++d0) {
                const int row = d0 * 16 + lr;
                const sx4 vb = *(const sx4*)(&lV[cur][row * 128 +
                                ((s0 ^ (row & 7)) << 4) + (g & 1) * 8]);
                acc[0][d0] = __builtin_amdgcn_mfma_f32_16x16x16bf16_1k(pa[0][ks], vb, acc[0][d0], 0, 0, 0);
                acc[1][d0] = __builtin_amdgcn_mfma_f32_16x16x16bf16_1k(pa[1][ks], vb, acc[1][d0], 0, 0, 0);
            }
        }
        __builtin_amdgcn_s_setprio(0);

        if (t + 1 < t1) __syncthreads();
        cur ^= 1;
    }

    // ---- epilogue: reduce l across g, write partial ----
    float ls0 = l_run[0];
    ls0 += __shfl_xor(ls0, 16);
    ls0 += __shfl_xor(ls0, 32);
    float ls1 = l_run[1];
    ls1 += __shfl_xor(ls1, 16);
    ls1 += __shfl_xor(ls1, 32);

    const int lmb = (h * 32 + p) * 128 + wid * 32 + lr;   // row index for lane<16

    if (c == 0) {                   // chunk0: raw f32 acc -> Og, lm planes 0/1
#pragma unroll
        for (int u = 0; u < 2; ++u)
#pragma unroll
            for (int d0 = 0; d0 < 4; ++d0)
#pragma unroll
                for (int r = 0; r < 4; ++r)
                    Oh[(size_t)(q0 + 16 * u + 4 * g + r) * DD + d0 * 16 + lr] = acc[u][d0][r];
        if (lane < 16) {
            lmW[lmb]               = m_run;
            lmW[lmb + 16]          = m_run;
            lmW[65536 + lmb]       = ls0;
            lmW[65536 + lmb + 16]  = ls1;
        }
    } else {                        // chunk1: bf16 acc -> accY, lm planes 2/3
        const size_t ab = (size_t)((h * 32 + p) * 128 + wid * 32) * 64;
#pragma unroll
        for (int u = 0; u < 2; ++u)
#pragma unroll
            for (int d0 = 0; d0 < 4; ++d0)
#pragma unroll
                for (int r = 0; r < 4; ++r) {
                    const __bf16 pb = (__bf16)acc[u][d0][r];
                    accY[ab + (size_t)(16 * u + 4 * g + r) * 64 + d0 * 16 + lr] =
                        __builtin_bit_cast(unsigned short, pb);
                }
        if (lane < 16) {
            lmW[131072 + lmb]      = m_run;
            lmW[131072 + lmb + 16] = m_run;
            lmW[196608 + lmb]      = ls0;
            lmW[196608 + lmb + 16] = ls1;
        }
    }
#undef STAGE
}

// ---------------- combine the two partials of every q-block ----------------
__global__ __launch_bounds__(256)
void combine_kernel(float* __restrict__ Og, const unsigned short* __restrict__ accY,
                    const float* __restrict__ lmW)
{
    const int blk = (int)blockIdx.x;      // 0..511 = (h, p)
    const int h = blk >> 5, p = blk & 31;
    const int t = threadIdx.x;
    const int col = t & 63;
    const int r0  = t >> 6;               // 0..3
    const int lmbase = (h * 32 + p) * 128;
    const size_t obase = ((size_t)h * SS + (size_t)p * QB) * DD;
    const size_t ybase = (size_t)lmbase * 64;

    for (int rr = 0; rr < 32; ++rr) {
        const int row = rr * 4 + r0;
        const float m0 = lmW[lmbase + row];
        const float l0 = lmW[65536 + lmbase + row];
        const float m1 = lmW[131072 + lmbase + row];
        const float l1 = lmW[196608 + lmbase + row];
        const float mm = fmaxf(m0, m1);
        const float a  = fast_exp2(m0 - mm);
        const float bb = fast_exp2(m1 - mm);
        const float den = a * l0 + bb * l1;
        const size_t oi = obase + (size_t)row * DD + col;
        const unsigned int yb = ((unsigned int)accY[ybase + (size_t)row * 64 + col]) << 16;
        const float yv = __builtin_bit_cast(float, yb);
        Og[oi] = (a * Og[oi] + bb * yv) / den;
    }
}

extern "C" void kernel_launch(void* const* d_in, const int* in_sizes, int n_in,
                              void* d_out, int out_size, void* d_ws, size_t ws_size,
                              hipStream_t stream)
{
    (void)in_sizes; (void)n_in; (void)out_size; (void)ws_size;
    const float* q = (const float*)d_in[0];
    const float* k = (const float*)d_in[1];
    const float* v = (const float*)d_in[2];
    float*       o = (float*)d_out;

    char* ws = (char*)d_ws;
    char*           Kimg = ws;                                     // 8 MB
    char*           Vimg = ws + ((size_t)1 << 23);                 // 8 MB
    unsigned short* accY = (unsigned short*)(ws + ((size_t)2 << 23)); // 8 MB bf16 partials
    float*          lmW  = (float*)(ws + ((size_t)3 << 23));       // 1 MB (4 x 65536 f32)

    hipLaunchKernelGGL(prep_kernel,    dim3(NH * NKV), dim3(256), 0, stream, k, v, Kimg, Vimg);
    hipLaunchKernelGGL(attn_fwd,       dim3(1024),     dim3(256), 0, stream, q, Kimg, Vimg, o, accY, lmW);
    hipLaunchKernelGGL(combine_kernel, dim3(512),      dim3(256), 0, stream, o, accY, lmW);
}